// Round 2
// baseline (196.368 us; speedup 1.0000x reference)
//
#include <hip/hip_runtime.h>
#include <hip/hip_bf16.h>
#include <math.h>
#include <stdint.h>

#define BB 4
#define TT 1024
#define EE 1024
#define HH 16
#define SS 64

typedef unsigned short ushort_t;
typedef __attribute__((ext_vector_type(8))) short bf16x8;
typedef __attribute__((ext_vector_type(8))) unsigned short u16x8;
typedef __attribute__((ext_vector_type(4))) unsigned short u16x4;
typedef __attribute__((ext_vector_type(4))) float f32x4;

__device__ __forceinline__ float b2f(ushort_t u) {
    union { float f; uint32_t i; } c;
    c.i = ((uint32_t)u) << 16;
    return c.f;
}
__device__ __forceinline__ ushort_t f2b(float f) {
    __hip_bfloat16 h = __float2bfloat16(f);
    return *(ushort_t*)&h;
}

// ---------------------------------------------------------------------------
// Kernel 0: fused fp32 -> bf16 converter, 4 elems/thread (Er then Wo)
// ---------------------------------------------------------------------------
__global__ __launch_bounds__(256) void cvt2_kernel(
    const float* __restrict__ a, ushort_t* __restrict__ da, int na,
    const float* __restrict__ b, ushort_t* __restrict__ db, int nb)
{
    const int i4 = (blockIdx.x * 256 + threadIdx.x) * 4;
    if (i4 < na) {
        const float4 xv = *(const float4*)&a[i4];
        u16x4 o4 = { f2b(xv.x), f2b(xv.y), f2b(xv.z), f2b(xv.w) };
        *(u16x4*)&da[i4] = o4;
    } else {
        const int j4 = i4 - na;
        if (j4 < nb) {
            const float4 xv = *(const float4*)&b[j4];
            u16x4 o4 = { f2b(xv.x), f2b(xv.y), f2b(xv.z), f2b(xv.w) };
            *(u16x4*)&db[j4] = o4;
        }
    }
}

// ---------------------------------------------------------------------------
// Kernel 1: MFMA q/k/v projection + fused vmean accumulation. (unchanged)
// ---------------------------------------------------------------------------
__global__ __launch_bounds__(256) void qkv_kernel(
    const float* __restrict__ x, const float* __restrict__ Wq,
    const float* __restrict__ Wk, const float* __restrict__ Wv,
    ushort_t* __restrict__ q, ushort_t* __restrict__ k, ushort_t* __restrict__ v,
    float* __restrict__ vmean)
{
    __shared__ __align__(16) ushort_t Xs[128][72];
    __shared__ __align__(16) ushort_t Wl[3][64][72];

    const int tid  = threadIdx.x;
    const int lane = tid & 63;
    const int w    = tid >> 6;
    const int m    = lane & 15;
    const int qd   = lane >> 4;
    const int n0   = blockIdx.x * 128;
    const int hh   = blockIdx.y;
    const int bb   = n0 >> 10;

#pragma unroll
    for (int l = 0; l < 8; l++) {
        const int idx = tid + 256 * l;
        const int row = idx >> 4;
        const int c4  = idx & 15;
        const float4 xv = *(const float4*)&x[(size_t)(n0 + row) * 1024 + hh * 64 + c4 * 4];
        u16x4 o4 = { f2b(xv.x), f2b(xv.y), f2b(xv.z), f2b(xv.w) };
        *(u16x4*)&Xs[row][c4 * 4] = o4;
    }
#pragma unroll
    for (int l = 0; l < 12; l++) {
        const int idx = tid + 256 * l;
        const int mo  = idx >> 10;
        const int r   = (idx >> 4) & 63;
        const int c4  = idx & 15;
        const float* W = (mo == 0) ? Wq : (mo == 1) ? Wk : Wv;
        const float4 wv = *(const float4*)&W[r * 64 + c4 * 4];
        u16x4 o4 = { f2b(wv.x), f2b(wv.y), f2b(wv.z), f2b(wv.w) };
        *(u16x4*)&Wl[mo][r][c4 * 4] = o4;
    }
    __syncthreads();

    f32x4 acc[2][3][4];
#pragma unroll
    for (int rt = 0; rt < 2; rt++)
#pragma unroll
        for (int mo = 0; mo < 3; mo++)
#pragma unroll
            for (int ct = 0; ct < 4; ct++) acc[rt][mo][ct] = {0.f, 0.f, 0.f, 0.f};

#pragma unroll
    for (int ks = 0; ks < 2; ks++) {
        bf16x8 af[2];
#pragma unroll
        for (int rt = 0; rt < 2; rt++)
            af[rt] = *(const bf16x8*)&Xs[32 * w + 16 * rt + m][ks * 32 + qd * 8];
#pragma unroll
        for (int mo = 0; mo < 3; mo++)
#pragma unroll
            for (int ct = 0; ct < 4; ct++) {
                bf16x8 bw = *(const bf16x8*)&Wl[mo][ct * 16 + m][ks * 32 + qd * 8];
#pragma unroll
                for (int rt = 0; rt < 2; rt++)
                    acc[rt][mo][ct] = __builtin_amdgcn_mfma_f32_16x16x32_bf16(
                        af[rt], bw, acc[rt][mo][ct], 0, 0, 0);
            }
    }

    const size_t obase = ((size_t)bb * HH + hh) * TT;
#pragma unroll
    for (int mo = 0; mo < 3; mo++) {
        ushort_t* dst = (mo == 0) ? q : (mo == 1) ? k : v;
        const float sc = (mo == 1) ? 0.03125f : 1.0f;
#pragma unroll
        for (int rt = 0; rt < 2; rt++)
#pragma unroll
            for (int reg = 0; reg < 4; reg++) {
                const int t = (n0 & 1023) + 32 * w + 16 * rt + qd * 4 + reg;
#pragma unroll
                for (int ct = 0; ct < 4; ct++)
                    dst[(obase + t) * SS + ct * 16 + m] = f2b(acc[rt][mo][ct][reg] * sc);
            }
    }

#pragma unroll
    for (int ct = 0; ct < 4; ct++) {
        float s = 0.f;
#pragma unroll
        for (int rt = 0; rt < 2; rt++)
#pragma unroll
            for (int reg = 0; reg < 4; reg++) s += acc[rt][2][ct][reg];
        s += __shfl_xor(s, 16);
        s += __shfl_xor(s, 32);
        if (qd == 0)
            atomicAdd(&vmean[(bb * HH + hh) * SS + ct * 16 + m], s);
    }
}

// ---------------------------------------------------------------------------
// Kernel 3: MFMA bf16 flash attention.  R2: 32-row i-tiles, 128-thread
// (2-wave) blocks, direct output ownership (no atomics).  Grid (64, 32) =
// 2048 blocks with trips 1..32; LDS 24.5KB -> 6 blocks/CU resident with
// refill (oversubscribed); yt = 31 - blockIdx.y gives LPT (longest first).
// Inner iteration is the verified R0 structure with Es ring 96 -> 64 rows
// (2-wave window is exactly 64) and w in {0,1}.
// ---------------------------------------------------------------------------
__global__ __launch_bounds__(128) void attn_kernel(
    const ushort_t* __restrict__ q, const ushort_t* __restrict__ k,
    const ushort_t* __restrict__ v, const ushort_t* __restrict__ er,
    const int* __restrict__ mask, const float* __restrict__ vmean,
    ushort_t* __restrict__ attn)
{
    __shared__ __align__(16) ushort_t Qs[32][72];
    __shared__ __align__(16) ushort_t Ks[32][72];
    __shared__ __align__(16) ushort_t Vt4[4][64][8];
    __shared__ __align__(16) ushort_t Es[64][72];
    __shared__ __align__(16) ushort_t Ps[2][16][40];

    const int tid  = threadIdx.x;
    const int lane = tid & 63;
    const int w    = tid >> 6;          // 0..1
    const int m    = lane & 15;
    const int qd   = lane >> 4;
    const int bh   = blockIdx.x;
    const int bb   = bh >> 4;
    const int hh   = bh & 15;
    const int yt   = 31 - blockIdx.y;   // LPT: longest blocks dispatched first
    const int i0   = yt * 32;
    const int steps = yt + 1;           // 32-wide j-steps (j up to i0+31)

    const ushort_t* qb = q + (size_t)bh * TT * SS;
    const ushort_t* kb = k + (size_t)bh * TT * SS;
    const ushort_t* vb = v + (size_t)bh * TT * SS;
    const ushort_t* eb = er + (size_t)hh * TT * SS;
    const int l0 = 960 - i0;            // can be -32 for i0=992

    // Q tile: 32 rows x 8 uint4
    for (int c = tid; c < 256; c += 128) {
        int row = c >> 3, sub = c & 7;
        *(uint4*)&Qs[row][sub * 8] = ((const uint4*)qb)[(size_t)(i0 + row) * 8 + sub];
    }
    // initial Er window: x in [0, 64) at slot x (ring of 64)
    for (int c = tid; c < 512; c += 128) {
        int row = c >> 3, sub = c & 7;
        int l = l0 + row;
        uint4 val = {0u, 0u, 0u, 0u};
        if ((unsigned)l <= 1023u) val = ((const uint4*)eb)[(size_t)l * 8 + sub];
        *(uint4*)&Es[row][sub * 8] = val;
    }

    const int krow = tid >> 3;          // 0..15 (two rows each: +0, +16)
    const int ksub = tid & 7;
    const int vd   = tid & 63;          // d index
    const int vh   = tid >> 6;          // 0..1 (two j-octets each)
    uint4 kreg[2], ereg[2];
    u16x8 vreg[2];

    {
#pragma unroll
        for (int rr = 0; rr < 2; rr++) {
            kreg[rr] = ((const uint4*)kb)[(size_t)(krow + 16 * rr) * 8 + ksub];
            const int l = l0 + 64 + krow + 16 * rr;
            ereg[rr] = (uint4){0u, 0u, 0u, 0u};
            if ((unsigned)l <= 1023u) ereg[rr] = ((const uint4*)eb)[(size_t)l * 8 + ksub];
        }
#pragma unroll
        for (int h = 0; h < 2; h++)
#pragma unroll
            for (int jj = 0; jj < 8; jj++)
                vreg[h][jj] = vb[(size_t)((vh * 2 + h) * 8 + jj) * SS + vd];
    }
    __syncthreads();

    bf16x8 aq[2];
#pragma unroll
    for (int ks = 0; ks < 2; ks++)
        aq[ks] = *(const bf16x8*)&Qs[16 * w + m][ks * 32 + qd * 8];

    f32x4 o[4];
#pragma unroll
    for (int vt = 0; vt < 4; vt++) o[vt] = {0.f, 0.f, 0.f, 0.f};
    float lsum[4] = {0.f, 0.f, 0.f, 0.f};

    const int ow = 48 - 16 * w;         // w=0 -> 48, w=1 -> 32
    const int srcbase = lane & 48;

    int j0 = 0;
    for (int t = 0; t < steps; ++t, j0 += 32) {
#pragma unroll
        for (int rr = 0; rr < 2; rr++) {
            *(uint4*)&Ks[krow + 16 * rr][ksub * 8] = kreg[rr];
            const int slot = (j0 & 63) + krow + 16 * rr;   // x = j0+64+.. mod 64
            *(uint4*)&Es[slot][ksub * 8] = ereg[rr];
        }
#pragma unroll
        for (int h = 0; h < 2; h++)
            *(u16x8*)&Vt4[vh * 2 + h][vd][0] = vreg[h];
        __syncthreads();

        if (t + 1 < steps) {
            const int jn = j0 + 32;
#pragma unroll
            for (int rr = 0; rr < 2; rr++) {
                kreg[rr] = ((const uint4*)kb)[(size_t)(jn + krow + 16 * rr) * 8 + ksub];
                const int l = l0 + 64 + jn + krow + 16 * rr;
                ereg[rr] = (uint4){0u, 0u, 0u, 0u};
                if ((unsigned)l <= 1023u) ereg[rr] = ((const uint4*)eb)[(size_t)l * 8 + ksub];
            }
#pragma unroll
            for (int h = 0; h < 2; h++)
#pragma unroll
                for (int jj = 0; jj < 8; jj++)
                    vreg[h][jj] = vb[(size_t)(jn + (vh * 2 + h) * 8 + jj) * SS + vd];
        }

        f32x4 s[2];
#pragma unroll
        for (int ct = 0; ct < 2; ct++) {
            s[ct] = {0.f, 0.f, 0.f, 0.f};
#pragma unroll
            for (int ks = 0; ks < 2; ks++) {
                bf16x8 bk = *(const bf16x8*)&Ks[16 * ct + m][ks * 32 + qd * 8];
                s[ct] = __builtin_amdgcn_mfma_f32_16x16x32_bf16(aq[ks], bk, s[ct], 0, 0, 0);
            }
        }
        f32x4 r[3];
#pragma unroll
        for (int rt = 0; rt < 3; rt++) {
            const int row0 = (ow + 16 * rt + j0) & 63;     // multiple of 16
            r[rt] = {0.f, 0.f, 0.f, 0.f};
#pragma unroll
            for (int ks = 0; ks < 2; ks++) {
                bf16x8 be = *(const bf16x8*)&Es[row0 + m][ks * 32 + qd * 8];
                r[rt] = __builtin_amdgcn_mfma_f32_16x16x32_bf16(aq[ks], be, r[rt], 0, 0, 0);
            }
        }

#pragma unroll
        for (int reg = 0; reg < 4; reg++) {
            const int r_ = qd * 4 + reg;
            const int i_ = i0 + 16 * w + r_;
            const int base = 15 - r_ + m;
            const int src  = srcbase | (base & 15);
            const float c0 = __shfl(r[0][reg], src);
            const float c1 = __shfl(r[1][reg], src);
            const float c2 = __shfl(r[2][reg], src);
            const float e0 = (base < 16) ? c0 : c1;
            const float e1 = (base < 16) ? c1 : c2;
            const float v0 = s[0][reg] + e0;
            const float v1 = s[1][reg] + e1;
            const float p0 = (j0 + m      > i_) ? 0.f : __expf(v0);
            const float p1 = (j0 + m + 16 > i_) ? 0.f : __expf(v1);
            lsum[reg] += p0 + p1;
            Ps[w][r_][m]      = f2b(p0);
            Ps[w][r_][m + 16] = f2b(p1);
        }

        bf16x8 pa = *(const bf16x8*)&Ps[w][m][qd * 8];
#pragma unroll
        for (int vt = 0; vt < 4; vt++) {
            bf16x8 bv = *(const bf16x8*)&Vt4[qd][16 * vt + m][0];
            o[vt] = __builtin_amdgcn_mfma_f32_16x16x32_bf16(pa, bv, o[vt], 0, 0, 0);
        }
        __syncthreads();
    }

    // ---- epilogue: direct write, block owns its 32 output rows ----
#pragma unroll
    for (int reg = 0; reg < 4; reg++) {
        float l = lsum[reg];
#pragma unroll
        for (int off = 1; off < 16; off <<= 1) l += __shfl_xor(l, off);
        const int r_ = qd * 4 + reg;
        const int i_ = i0 + 16 * w + r_;
        const bool pad = (mask[bb * TT + i_] == 0);
        const float inv = 1.0f / l;
        const size_t rowbase = ((size_t)bb * TT + hh * 64 + (i_ >> 4)) * EE + (i_ & 15) * 64;
#pragma unroll
        for (int vt = 0; vt < 4; vt++) {
            const int d_ = 16 * vt + m;
            float val = pad ? vmean[bh * SS + d_] * (1.0f / 1024.0f)
                            : o[vt][reg] * inv;
            attn[rowbase + d_] = f2b(val);
        }
    }
}

// ---------------------------------------------------------------------------
// Kernel 4: MFMA bf16 GEMM  out = M @ Wo16^T + bo  (unchanged)
// ---------------------------------------------------------------------------
__global__ __launch_bounds__(256) void outproj_kernel(
    const ushort_t* __restrict__ A, const ushort_t* __restrict__ Wo,
    const float* __restrict__ bo, float* __restrict__ out)
{
    __shared__ __align__(16) ushort_t As[128][36];
    __shared__ __align__(16) ushort_t Bs[128][36];

    const int tid  = threadIdx.x;
    const int lane = tid & 63;
    const int w    = tid >> 6;
    const int m    = lane & 15;
    const int qd   = lane >> 4;
    const int wrow = (w & 1) * 64;
    const int wcol = (w >> 1) * 64;
    const int o0   = blockIdx.x * 128;
    const int n0   = blockIdx.y * 128;

    f32x4 acc[4][4];
#pragma unroll
    for (int rt = 0; rt < 4; rt++)
#pragma unroll
        for (int ct = 0; ct < 4; ct++) acc[rt][ct] = {0.f, 0.f, 0.f, 0.f};

    for (int k0 = 0; k0 < 1024; k0 += 32) {
        __syncthreads();
#pragma unroll
        for (int l = 0; l < 2; l++) {
            const int idx = tid + 256 * l;
            const int row = idx >> 2;
            const int sub = idx & 3;
            *(uint4*)&As[row][sub * 8] =
                *(const uint4*)&A[(size_t)(n0 + row) * 1024 + k0 + sub * 8];
            *(uint4*)&Bs[row][sub * 8] =
                *(const uint4*)&Wo[(size_t)(o0 + row) * 1024 + k0 + sub * 8];
        }
        __syncthreads();

        bf16x8 af[4], bf[4];
#pragma unroll
        for (int rt = 0; rt < 4; rt++)
            af[rt] = *(const bf16x8*)&As[wrow + rt * 16 + m][qd * 8];
#pragma unroll
        for (int ct = 0; ct < 4; ct++)
            bf[ct] = *(const bf16x8*)&Bs[wcol + ct * 16 + m][qd * 8];
#pragma unroll
        for (int rt = 0; rt < 4; rt++)
#pragma unroll
            for (int ct = 0; ct < 4; ct++)
                acc[rt][ct] = __builtin_amdgcn_mfma_f32_16x16x32_bf16(
                    af[rt], bf[ct], acc[rt][ct], 0, 0, 0);
    }

#pragma unroll
    for (int rt = 0; rt < 4; rt++) {
#pragma unroll
        for (int ct = 0; ct < 4; ct++) {
            const int oc = o0 + wcol + ct * 16 + m;
            const float bias = bo[oc];
#pragma unroll
            for (int reg = 0; reg < 4; reg++) {
                const int n = n0 + wrow + rt * 16 + qd * 4 + reg;
                out[(size_t)n * EE + oc] = acc[rt][ct][reg] + bias;
            }
        }
    }
}

// ---------------------------------------------------------------------------
// Launcher.  ws (ushort): q16|k16|v16 (4M each) | er16 (1M) | wo16 (1M)
//            | M16 (4M) | vmean f32 (4096)
// ---------------------------------------------------------------------------
extern "C" void kernel_launch(void* const* d_in, const int* in_sizes, int n_in,
                              void* d_out, int out_size, void* d_ws, size_t ws_size,
                              hipStream_t stream)
{
    const float* x    = (const float*)d_in[0];
    const int*   mask = (const int*)d_in[1];
    const float* Wq   = (const float*)d_in[2];
    const float* Wk   = (const float*)d_in[3];
    const float* Wv   = (const float*)d_in[4];
    const float* Er   = (const float*)d_in[5];
    const float* Wo   = (const float*)d_in[6];
    const float* bo   = (const float*)d_in[7];
    float* out = (float*)d_out;

    const size_t QKV = (size_t)BB * HH * TT * SS;
    const int    nEr = HH * TT * SS;
    const int    nWo = EE * EE;
    ushort_t* q16   = (ushort_t*)d_ws;
    ushort_t* k16   = q16 + QKV;
    ushort_t* v16   = k16 + QKV;
    ushort_t* er16  = v16 + QKV;
    ushort_t* wo16  = er16 + nEr;
    ushort_t* M16   = wo16 + nWo;
    float*    vmean = (float*)(M16 + QKV);

    hipMemsetAsync(vmean, 0, BB * HH * SS * sizeof(float), stream);
    cvt2_kernel<<<dim3((nEr + nWo) / 1024), 256, 0, stream>>>(Er, er16, nEr, Wo, wo16, nWo);
    qkv_kernel<<<dim3(BB * TT / 128, HH), 256, 0, stream>>>(x, Wq, Wk, Wv, q16, k16, v16, vmean);
    attn_kernel<<<dim3(BB * HH, TT / 32), 128, 0, stream>>>(q16, k16, v16, er16, mask, vmean, M16);
    outproj_kernel<<<dim3(EE / 128, BB * TT / 128), 256, 0, stream>>>(M16, wo16, bo, out);
}

// Round 3
// 182.539 us; speedup vs baseline: 1.0758x; 1.0758x over previous
//
#include <hip/hip_runtime.h>
#include <hip/hip_bf16.h>
#include <math.h>
#include <stdint.h>

#define BB 4
#define TT 1024
#define EE 1024
#define HH 16
#define SS 64

typedef unsigned short ushort_t;
typedef __attribute__((ext_vector_type(8))) short bf16x8;
typedef __attribute__((ext_vector_type(8))) unsigned short u16x8;
typedef __attribute__((ext_vector_type(4))) unsigned short u16x4;
typedef __attribute__((ext_vector_type(4))) float f32x4;

__device__ __forceinline__ float b2f(ushort_t u) {
    union { float f; uint32_t i; } c;
    c.i = ((uint32_t)u) << 16;
    return c.f;
}
__device__ __forceinline__ ushort_t f2b(float f) {
    __hip_bfloat16 h = __float2bfloat16(f);
    return *(ushort_t*)&h;
}

// ---------------------------------------------------------------------------
// Kernel 0: fused fp32 -> bf16 converter, 4 elems/thread (Er then Wo)
// ---------------------------------------------------------------------------
__global__ __launch_bounds__(256) void cvt2_kernel(
    const float* __restrict__ a, ushort_t* __restrict__ da, int na,
    const float* __restrict__ b, ushort_t* __restrict__ db, int nb)
{
    const int i4 = (blockIdx.x * 256 + threadIdx.x) * 4;
    if (i4 < na) {
        const float4 xv = *(const float4*)&a[i4];
        u16x4 o4 = { f2b(xv.x), f2b(xv.y), f2b(xv.z), f2b(xv.w) };
        *(u16x4*)&da[i4] = o4;
    } else {
        const int j4 = i4 - na;
        if (j4 < nb) {
            const float4 xv = *(const float4*)&b[j4];
            u16x4 o4 = { f2b(xv.x), f2b(xv.y), f2b(xv.z), f2b(xv.w) };
            *(u16x4*)&db[j4] = o4;
        }
    }
}

// ---------------------------------------------------------------------------
// Kernel 1: MFMA q/k/v projection + fused vmean accumulation. (unchanged)
// ---------------------------------------------------------------------------
__global__ __launch_bounds__(256) void qkv_kernel(
    const float* __restrict__ x, const float* __restrict__ Wq,
    const float* __restrict__ Wk, const float* __restrict__ Wv,
    ushort_t* __restrict__ q, ushort_t* __restrict__ k, ushort_t* __restrict__ v,
    float* __restrict__ vmean)
{
    __shared__ __align__(16) ushort_t Xs[128][72];
    __shared__ __align__(16) ushort_t Wl[3][64][72];

    const int tid  = threadIdx.x;
    const int lane = tid & 63;
    const int w    = tid >> 6;
    const int m    = lane & 15;
    const int qd   = lane >> 4;
    const int n0   = blockIdx.x * 128;
    const int hh   = blockIdx.y;
    const int bb   = n0 >> 10;

#pragma unroll
    for (int l = 0; l < 8; l++) {
        const int idx = tid + 256 * l;
        const int row = idx >> 4;
        const int c4  = idx & 15;
        const float4 xv = *(const float4*)&x[(size_t)(n0 + row) * 1024 + hh * 64 + c4 * 4];
        u16x4 o4 = { f2b(xv.x), f2b(xv.y), f2b(xv.z), f2b(xv.w) };
        *(u16x4*)&Xs[row][c4 * 4] = o4;
    }
#pragma unroll
    for (int l = 0; l < 12; l++) {
        const int idx = tid + 256 * l;
        const int mo  = idx >> 10;
        const int r   = (idx >> 4) & 63;
        const int c4  = idx & 15;
        const float* W = (mo == 0) ? Wq : (mo == 1) ? Wk : Wv;
        const float4 wv = *(const float4*)&W[r * 64 + c4 * 4];
        u16x4 o4 = { f2b(wv.x), f2b(wv.y), f2b(wv.z), f2b(wv.w) };
        *(u16x4*)&Wl[mo][r][c4 * 4] = o4;
    }
    __syncthreads();

    f32x4 acc[2][3][4];
#pragma unroll
    for (int rt = 0; rt < 2; rt++)
#pragma unroll
        for (int mo = 0; mo < 3; mo++)
#pragma unroll
            for (int ct = 0; ct < 4; ct++) acc[rt][mo][ct] = {0.f, 0.f, 0.f, 0.f};

#pragma unroll
    for (int ks = 0; ks < 2; ks++) {
        bf16x8 af[2];
#pragma unroll
        for (int rt = 0; rt < 2; rt++)
            af[rt] = *(const bf16x8*)&Xs[32 * w + 16 * rt + m][ks * 32 + qd * 8];
#pragma unroll
        for (int mo = 0; mo < 3; mo++)
#pragma unroll
            for (int ct = 0; ct < 4; ct++) {
                bf16x8 bw = *(const bf16x8*)&Wl[mo][ct * 16 + m][ks * 32 + qd * 8];
#pragma unroll
                for (int rt = 0; rt < 2; rt++)
                    acc[rt][mo][ct] = __builtin_amdgcn_mfma_f32_16x16x32_bf16(
                        af[rt], bw, acc[rt][mo][ct], 0, 0, 0);
            }
    }

    const size_t obase = ((size_t)bb * HH + hh) * TT;
#pragma unroll
    for (int mo = 0; mo < 3; mo++) {
        ushort_t* dst = (mo == 0) ? q : (mo == 1) ? k : v;
        const float sc = (mo == 1) ? 0.03125f : 1.0f;
#pragma unroll
        for (int rt = 0; rt < 2; rt++)
#pragma unroll
            for (int reg = 0; reg < 4; reg++) {
                const int t = (n0 & 1023) + 32 * w + 16 * rt + qd * 4 + reg;
#pragma unroll
                for (int ct = 0; ct < 4; ct++)
                    dst[(obase + t) * SS + ct * 16 + m] = f2b(acc[rt][mo][ct][reg] * sc);
            }
    }

#pragma unroll
    for (int ct = 0; ct < 4; ct++) {
        float s = 0.f;
#pragma unroll
        for (int rt = 0; rt < 2; rt++)
#pragma unroll
            for (int reg = 0; reg < 4; reg++) s += acc[rt][2][ct][reg];
        s += __shfl_xor(s, 16);
        s += __shfl_xor(s, 32);
        if (qd == 0)
            atomicAdd(&vmean[(bb * HH + hh) * SS + ct * 16 + m], s);
    }
}

// ---------------------------------------------------------------------------
// Kernel 3: MFMA bf16 flash attention.  R3: R0's verified 64-row/4-wave
// structure with 64-WIDE j-steps (half the steps, half the barriers, fatter
// per-step ILP).  Qs LDS dropped (aq loaded direct to regs).  Es is a
// 128-row ring = exact read window [j0, j0+128) of the skew at 64-wide;
// next-step writes clobber precisely the rows read last step, protected by
// the end-of-step barrier (same invariant as R0's 96-ring).
// LDS 45KB -> 3 blocks/CU; grid 1024 > 768 slots -> refill; LPT order.
// ---------------------------------------------------------------------------
__global__ __launch_bounds__(256) void attn_kernel(
    const ushort_t* __restrict__ q, const ushort_t* __restrict__ k,
    const ushort_t* __restrict__ v, const ushort_t* __restrict__ er,
    const int* __restrict__ mask, const float* __restrict__ vmean,
    ushort_t* __restrict__ attn)
{
    __shared__ __align__(16) ushort_t Ks[64][72];
    __shared__ __align__(16) ushort_t Vt4[8][64][8];
    __shared__ __align__(16) ushort_t Es[128][72];
    __shared__ __align__(16) ushort_t Ps[4][16][72];

    const int tid  = threadIdx.x;
    const int lane = tid & 63;
    const int w    = tid >> 6;
    const int m    = lane & 15;
    const int qd   = lane >> 4;
    const int bh   = blockIdx.x;
    const int bb   = bh >> 4;
    const int hh   = bh & 15;
    const int yt   = 15 - blockIdx.y;   // LPT: 16-step blocks dispatched first
    const int i0   = yt * 64;
    const int steps = yt + 1;           // 64-wide j-steps

    const ushort_t* qb = q + (size_t)bh * TT * SS;
    const ushort_t* kb = k + (size_t)bh * TT * SS;
    const ushort_t* vb = v + (size_t)bh * TT * SS;
    const ushort_t* eb = er + (size_t)hh * TT * SS;
    const int l0 = 960 - i0;

    // prologue: Es rows x in [0,64) direct to ring slots 0..63
    for (int c = tid; c < 512; c += 256) {
        int row = c >> 3, sub = c & 7;
        int l = l0 + row;
        uint4 val = {0u, 0u, 0u, 0u};
        if ((unsigned)l <= 1023u) val = ((const uint4*)eb)[(size_t)l * 8 + sub];
        *(uint4*)&Es[row][sub * 8] = val;
    }

    const int krow = tid >> 3;          // 0..31 (rows +0, +32)
    const int ksub = tid & 7;
    const int vd   = tid & 63;
    const int vjh  = tid >> 6;          // 0..3 (groups vjh, vjh+4)
    uint4 kreg[2], ereg[2];
    u16x8 vreg[2];

    {
#pragma unroll
        for (int rr = 0; rr < 2; rr++) {
            kreg[rr] = ((const uint4*)kb)[(size_t)(krow + 32 * rr) * 8 + ksub];
            const int l = l0 + 64 + krow + 32 * rr;      // x in [64,128)
            ereg[rr] = (uint4){0u, 0u, 0u, 0u};
            if ((unsigned)l <= 1023u) ereg[rr] = ((const uint4*)eb)[(size_t)l * 8 + ksub];
        }
#pragma unroll
        for (int h = 0; h < 2; h++)
#pragma unroll
            for (int jj = 0; jj < 8; jj++)
                vreg[h][jj] = vb[(size_t)((vjh + 4 * h) * 8 + jj) * SS + vd];
    }

    // Q fragments direct from global (once per block)
    bf16x8 aq[2];
#pragma unroll
    for (int ks = 0; ks < 2; ks++)
        aq[ks] = *(const bf16x8*)&qb[(size_t)(i0 + 16 * w + m) * SS + ks * 32 + qd * 8];

    __syncthreads();

    f32x4 o[4];
#pragma unroll
    for (int vt = 0; vt < 4; vt++) o[vt] = {0.f, 0.f, 0.f, 0.f};
    float lsum[4] = {0.f, 0.f, 0.f, 0.f};

    const int ow = 48 - 16 * w;
    const int srcbase = lane & 48;

    int j0 = 0;
    for (int t = 0; t < steps; ++t, j0 += 64) {
        // phase 1: commit staged regs to LDS
#pragma unroll
        for (int rr = 0; rr < 2; rr++) {
            *(uint4*)&Ks[krow + 32 * rr][ksub * 8] = kreg[rr];
            const int slot = ((j0 + 64) & 127) + krow + 32 * rr;  // x=j0+64+..
            *(uint4*)&Es[slot][ksub * 8] = ereg[rr];
        }
#pragma unroll
        for (int h = 0; h < 2; h++)
            *(u16x8*)&Vt4[vjh + 4 * h][vd][0] = vreg[h];
        __syncthreads();

        // phase 2: prefetch next step
        if (t + 1 < steps) {
            const int jn = j0 + 64;
#pragma unroll
            for (int rr = 0; rr < 2; rr++) {
                kreg[rr] = ((const uint4*)kb)[(size_t)(jn + krow + 32 * rr) * 8 + ksub];
                const int l = l0 + jn + 64 + krow + 32 * rr;   // x in [jn+64,jn+128)
                ereg[rr] = (uint4){0u, 0u, 0u, 0u};
                if ((unsigned)l <= 1023u) ereg[rr] = ((const uint4*)eb)[(size_t)l * 8 + ksub];
            }
#pragma unroll
            for (int h = 0; h < 2; h++)
#pragma unroll
                for (int jj = 0; jj < 8; jj++)
                    vreg[h][jj] = vb[(size_t)(jn + (vjh + 4 * h) * 8 + jj) * SS + vd];
        }

        // phase 3: QK^T (4 col-tiles x 64 cols)
        f32x4 s[4];
#pragma unroll
        for (int ct = 0; ct < 4; ct++) {
            s[ct] = {0.f, 0.f, 0.f, 0.f};
#pragma unroll
            for (int ks = 0; ks < 2; ks++) {
                bf16x8 bk = *(const bf16x8*)&Ks[16 * ct + m][ks * 32 + qd * 8];
                s[ct] = __builtin_amdgcn_mfma_f32_16x16x32_bf16(aq[ks], bk, s[ct], 0, 0, 0);
            }
        }
        // Q x Er: 5 diagonal tiles cover x in [j0+ow, j0+ow+80)
        f32x4 r[5];
#pragma unroll
        for (int rt = 0; rt < 5; rt++) {
            const int row0 = (ow + 16 * rt + j0) & 127;    // 16-multiple, no wrap +m
            r[rt] = {0.f, 0.f, 0.f, 0.f};
#pragma unroll
            for (int ks = 0; ks < 2; ks++) {
                bf16x8 be = *(const bf16x8*)&Es[row0 + m][ks * 32 + qd * 8];
                r[rt] = __builtin_amdgcn_mfma_f32_16x16x32_bf16(aq[ks], be, r[rt], 0, 0, 0);
            }
        }

        // phase 4: skew-diagonal extract + softmax numerator, 4 col-groups
#pragma unroll
        for (int reg = 0; reg < 4; reg++) {
            const int r_ = qd * 4 + reg;
            const int i_ = i0 + 16 * w + r_;
            const int base = 15 - r_ + m;
            const int src  = srcbase | (base & 15);
            float sc[5];
#pragma unroll
            for (int rt = 0; rt < 5; rt++) sc[rt] = __shfl(r[rt][reg], src);
#pragma unroll
            for (int c = 0; c < 4; c++) {
                const float e  = (base < 16) ? sc[c] : sc[c + 1];
                const float vv = s[c][reg] + e;
                const float p  = (j0 + m + 16 * c > i_) ? 0.f : __expf(vv);
                lsum[reg] += p;
                Ps[w][r_][m + 16 * c] = f2b(p);
            }
        }

        // phase 5: PV over both 32-col halves
#pragma unroll
        for (int h = 0; h < 2; h++) {
            bf16x8 pa = *(const bf16x8*)&Ps[w][m][32 * h + qd * 8];
#pragma unroll
            for (int vt = 0; vt < 4; vt++) {
                bf16x8 bv = *(const bf16x8*)&Vt4[4 * h + qd][16 * vt + m][0];
                o[vt] = __builtin_amdgcn_mfma_f32_16x16x32_bf16(pa, bv, o[vt], 0, 0, 0);
            }
        }
        __syncthreads();
    }

    // epilogue: direct write, block owns its 64 output rows
#pragma unroll
    for (int reg = 0; reg < 4; reg++) {
        float l = lsum[reg];
#pragma unroll
        for (int off = 1; off < 16; off <<= 1) l += __shfl_xor(l, off);
        const int r_ = qd * 4 + reg;
        const int i_ = i0 + 16 * w + r_;
        const bool pad = (mask[bb * TT + i_] == 0);
        const float inv = 1.0f / l;
        const size_t rowbase = ((size_t)bb * TT + hh * 64 + (i_ >> 4)) * EE + (i_ & 15) * 64;
#pragma unroll
        for (int vt = 0; vt < 4; vt++) {
            const int d_ = 16 * vt + m;
            float val = pad ? vmean[bh * SS + d_] * (1.0f / 1024.0f)
                            : o[vt][reg] * inv;
            attn[rowbase + d_] = f2b(val);
        }
    }
}

// ---------------------------------------------------------------------------
// Kernel 4: MFMA bf16 GEMM  out = M @ Wo16^T + bo  (unchanged)
// ---------------------------------------------------------------------------
__global__ __launch_bounds__(256) void outproj_kernel(
    const ushort_t* __restrict__ A, const ushort_t* __restrict__ Wo,
    const float* __restrict__ bo, float* __restrict__ out)
{
    __shared__ __align__(16) ushort_t As[128][36];
    __shared__ __align__(16) ushort_t Bs[128][36];

    const int tid  = threadIdx.x;
    const int lane = tid & 63;
    const int w    = tid >> 6;
    const int m    = lane & 15;
    const int qd   = lane >> 4;
    const int wrow = (w & 1) * 64;
    const int wcol = (w >> 1) * 64;
    const int o0   = blockIdx.x * 128;
    const int n0   = blockIdx.y * 128;

    f32x4 acc[4][4];
#pragma unroll
    for (int rt = 0; rt < 4; rt++)
#pragma unroll
        for (int ct = 0; ct < 4; ct++) acc[rt][ct] = {0.f, 0.f, 0.f, 0.f};

    for (int k0 = 0; k0 < 1024; k0 += 32) {
        __syncthreads();
#pragma unroll
        for (int l = 0; l < 2; l++) {
            const int idx = tid + 256 * l;
            const int row = idx >> 2;
            const int sub = idx & 3;
            *(uint4*)&As[row][sub * 8] =
                *(const uint4*)&A[(size_t)(n0 + row) * 1024 + k0 + sub * 8];
            *(uint4*)&Bs[row][sub * 8] =
                *(const uint4*)&Wo[(size_t)(o0 + row) * 1024 + k0 + sub * 8];
        }
        __syncthreads();

        bf16x8 af[4], bf[4];
#pragma unroll
        for (int rt = 0; rt < 4; rt++)
            af[rt] = *(const bf16x8*)&As[wrow + rt * 16 + m][qd * 8];
#pragma unroll
        for (int ct = 0; ct < 4; ct++)
            bf[ct] = *(const bf16x8*)&Bs[wcol + ct * 16 + m][qd * 8];
#pragma unroll
        for (int rt = 0; rt < 4; rt++)
#pragma unroll
            for (int ct = 0; ct < 4; ct++)
                acc[rt][ct] = __builtin_amdgcn_mfma_f32_16x16x32_bf16(
                    af[rt], bf[ct], acc[rt][ct], 0, 0, 0);
    }

#pragma unroll
    for (int rt = 0; rt < 4; rt++) {
#pragma unroll
        for (int ct = 0; ct < 4; ct++) {
            const int oc = o0 + wcol + ct * 16 + m;
            const float bias = bo[oc];
#pragma unroll
            for (int reg = 0; reg < 4; reg++) {
                const int n = n0 + wrow + rt * 16 + qd * 4 + reg;
                out[(size_t)n * EE + oc] = acc[rt][ct][reg] + bias;
            }
        }
    }
}

// ---------------------------------------------------------------------------
// Launcher.  ws (ushort): q16|k16|v16 (4M each) | er16 (1M) | wo16 (1M)
//            | M16 (4M) | vmean f32 (4096)
// ---------------------------------------------------------------------------
extern "C" void kernel_launch(void* const* d_in, const int* in_sizes, int n_in,
                              void* d_out, int out_size, void* d_ws, size_t ws_size,
                              hipStream_t stream)
{
    const float* x    = (const float*)d_in[0];
    const int*   mask = (const int*)d_in[1];
    const float* Wq   = (const float*)d_in[2];
    const float* Wk   = (const float*)d_in[3];
    const float* Wv   = (const float*)d_in[4];
    const float* Er   = (const float*)d_in[5];
    const float* Wo   = (const float*)d_in[6];
    const float* bo   = (const float*)d_in[7];
    float* out = (float*)d_out;

    const size_t QKV = (size_t)BB * HH * TT * SS;
    const int    nEr = HH * TT * SS;
    const int    nWo = EE * EE;
    ushort_t* q16   = (ushort_t*)d_ws;
    ushort_t* k16   = q16 + QKV;
    ushort_t* v16   = k16 + QKV;
    ushort_t* er16  = v16 + QKV;
    ushort_t* wo16  = er16 + nEr;
    ushort_t* M16   = wo16 + nWo;
    float*    vmean = (float*)(M16 + QKV);

    hipMemsetAsync(vmean, 0, BB * HH * SS * sizeof(float), stream);
    cvt2_kernel<<<dim3((nEr + nWo) / 1024), 256, 0, stream>>>(Er, er16, nEr, Wo, wo16, nWo);
    qkv_kernel<<<dim3(BB * TT / 128, HH), 256, 0, stream>>>(x, Wq, Wk, Wv, q16, k16, v16, vmean);
    attn_kernel<<<dim3(BB * HH, TT / 64), 256, 0, stream>>>(q16, k16, v16, er16, mask, vmean, M16);
    outproj_kernel<<<dim3(EE / 128, BB * TT / 128), 256, 0, stream>>>(M16, wo16, bo, out);
}

// Round 4
// 178.487 us; speedup vs baseline: 1.1002x; 1.0227x over previous
//
#include <hip/hip_runtime.h>
#include <hip/hip_bf16.h>
#include <math.h>
#include <stdint.h>

#define BB 4
#define TT 1024
#define EE 1024
#define HH 16
#define SS 64

typedef unsigned short ushort_t;
typedef __attribute__((ext_vector_type(8))) short bf16x8;
typedef __attribute__((ext_vector_type(8))) unsigned short u16x8;
typedef __attribute__((ext_vector_type(4))) unsigned short u16x4;
typedef __attribute__((ext_vector_type(4))) float f32x4;

__device__ __forceinline__ float b2f(ushort_t u) {
    union { float f; uint32_t i; } c;
    c.i = ((uint32_t)u) << 16;
    return c.f;
}
__device__ __forceinline__ ushort_t f2b(float f) {
    __hip_bfloat16 h = __float2bfloat16(f);
    return *(ushort_t*)&h;
}

// ---------------------------------------------------------------------------
// Kernel 0: fused fp32 -> bf16 converter, 4 elems/thread (Er then Wo)
// ---------------------------------------------------------------------------
__global__ __launch_bounds__(256) void cvt2_kernel(
    const float* __restrict__ a, ushort_t* __restrict__ da, int na,
    const float* __restrict__ b, ushort_t* __restrict__ db, int nb)
{
    const int i4 = (blockIdx.x * 256 + threadIdx.x) * 4;
    if (i4 < na) {
        const float4 xv = *(const float4*)&a[i4];
        u16x4 o4 = { f2b(xv.x), f2b(xv.y), f2b(xv.z), f2b(xv.w) };
        *(u16x4*)&da[i4] = o4;
    } else {
        const int j4 = i4 - na;
        if (j4 < nb) {
            const float4 xv = *(const float4*)&b[j4];
            u16x4 o4 = { f2b(xv.x), f2b(xv.y), f2b(xv.z), f2b(xv.w) };
            *(u16x4*)&db[j4] = o4;
        }
    }
}

// ---------------------------------------------------------------------------
// Kernel 1: MFMA q/k/v projection + fused vmean accumulation. (unchanged)
// ---------------------------------------------------------------------------
__global__ __launch_bounds__(256) void qkv_kernel(
    const float* __restrict__ x, const float* __restrict__ Wq,
    const float* __restrict__ Wk, const float* __restrict__ Wv,
    ushort_t* __restrict__ q, ushort_t* __restrict__ k, ushort_t* __restrict__ v,
    float* __restrict__ vmean)
{
    __shared__ __align__(16) ushort_t Xs[128][72];
    __shared__ __align__(16) ushort_t Wl[3][64][72];

    const int tid  = threadIdx.x;
    const int lane = tid & 63;
    const int w    = tid >> 6;
    const int m    = lane & 15;
    const int qd   = lane >> 4;
    const int n0   = blockIdx.x * 128;
    const int hh   = blockIdx.y;
    const int bb   = n0 >> 10;

#pragma unroll
    for (int l = 0; l < 8; l++) {
        const int idx = tid + 256 * l;
        const int row = idx >> 4;
        const int c4  = idx & 15;
        const float4 xv = *(const float4*)&x[(size_t)(n0 + row) * 1024 + hh * 64 + c4 * 4];
        u16x4 o4 = { f2b(xv.x), f2b(xv.y), f2b(xv.z), f2b(xv.w) };
        *(u16x4*)&Xs[row][c4 * 4] = o4;
    }
#pragma unroll
    for (int l = 0; l < 12; l++) {
        const int idx = tid + 256 * l;
        const int mo  = idx >> 10;
        const int r   = (idx >> 4) & 63;
        const int c4  = idx & 15;
        const float* W = (mo == 0) ? Wq : (mo == 1) ? Wk : Wv;
        const float4 wv = *(const float4*)&W[r * 64 + c4 * 4];
        u16x4 o4 = { f2b(wv.x), f2b(wv.y), f2b(wv.z), f2b(wv.w) };
        *(u16x4*)&Wl[mo][r][c4 * 4] = o4;
    }
    __syncthreads();

    f32x4 acc[2][3][4];
#pragma unroll
    for (int rt = 0; rt < 2; rt++)
#pragma unroll
        for (int mo = 0; mo < 3; mo++)
#pragma unroll
            for (int ct = 0; ct < 4; ct++) acc[rt][mo][ct] = {0.f, 0.f, 0.f, 0.f};

#pragma unroll
    for (int ks = 0; ks < 2; ks++) {
        bf16x8 af[2];
#pragma unroll
        for (int rt = 0; rt < 2; rt++)
            af[rt] = *(const bf16x8*)&Xs[32 * w + 16 * rt + m][ks * 32 + qd * 8];
#pragma unroll
        for (int mo = 0; mo < 3; mo++)
#pragma unroll
            for (int ct = 0; ct < 4; ct++) {
                bf16x8 bw = *(const bf16x8*)&Wl[mo][ct * 16 + m][ks * 32 + qd * 8];
#pragma unroll
                for (int rt = 0; rt < 2; rt++)
                    acc[rt][mo][ct] = __builtin_amdgcn_mfma_f32_16x16x32_bf16(
                        af[rt], bw, acc[rt][mo][ct], 0, 0, 0);
            }
    }

    const size_t obase = ((size_t)bb * HH + hh) * TT;
#pragma unroll
    for (int mo = 0; mo < 3; mo++) {
        ushort_t* dst = (mo == 0) ? q : (mo == 1) ? k : v;
        const float sc = (mo == 1) ? 0.03125f : 1.0f;
#pragma unroll
        for (int rt = 0; rt < 2; rt++)
#pragma unroll
            for (int reg = 0; reg < 4; reg++) {
                const int t = (n0 & 1023) + 32 * w + 16 * rt + qd * 4 + reg;
#pragma unroll
                for (int ct = 0; ct < 4; ct++)
                    dst[(obase + t) * SS + ct * 16 + m] = f2b(acc[rt][mo][ct][reg] * sc);
            }
    }

#pragma unroll
    for (int ct = 0; ct < 4; ct++) {
        float s = 0.f;
#pragma unroll
        for (int rt = 0; rt < 2; rt++)
#pragma unroll
            for (int reg = 0; reg < 4; reg++) s += acc[rt][2][ct][reg];
        s += __shfl_xor(s, 16);
        s += __shfl_xor(s, 32);
        if (qd == 0)
            atomicAdd(&vmean[(bb * HH + hh) * SS + ct * 16 + m], s);
    }
}

// ---------------------------------------------------------------------------
// Kernel 3: MFMA bf16 flash attention.  R4: j-split-within-block.
// 512 threads = 8 waves; waves 0-3 (grp 0) run R0's verified step at even
// 32-wide j-tiles (myj0 = 64t), waves 4-7 (grp 1) at odd (myj0 = 64t+32).
// Both groups do exactly yt+1 iterations; partial (o, lsum) combined via
// LDS at the epilogue (no atomics, no extra HBM traffic).  K fragments are
// gathered direct from global (L1/L2-hit; tile is 4KB, reused by 4 waves).
// Es = 192-row ring (3-phase rotation, same invariant as R0's 96-ring).
// LDS 46080 B -> 3 blocks/CU = 24 waves; 1024 blocks > 768 slots -> refill;
// LPT dispatch (longest tiles first).  VGPR pinned <=64 for 8 waves/SIMD.
// ---------------------------------------------------------------------------
__global__ __launch_bounds__(512, 8) void attn_kernel(
    const ushort_t* __restrict__ q, const ushort_t* __restrict__ k,
    const ushort_t* __restrict__ v, const ushort_t* __restrict__ er,
    const int* __restrict__ mask, const float* __restrict__ vmean,
    ushort_t* __restrict__ attn)
{
    __shared__ __align__(16) ushort_t Vt4[8][64][8];   //  8192 B, j = idx0*8+jj
    __shared__ __align__(16) ushort_t Es[192][72];     // 27648 B, ring x%192
    __shared__ __align__(16) ushort_t Ps[8][16][40];   // 10240 B, per-wave

    const int tid  = threadIdx.x;
    const int lane = tid & 63;
    const int w    = tid >> 6;          // 0..7
    const int grp  = w >> 2;            // 0 = even j-tiles, 1 = odd
    const int wl   = w & 3;             // row-group role (R0's w)
    const int m    = lane & 15;
    const int qd   = lane >> 4;
    const int bh   = blockIdx.x;
    const int bb   = bh >> 4;
    const int hh   = bh & 15;
    const int yt   = 15 - blockIdx.y;   // LPT
    const int i0   = yt * 64;
    const int steps = yt + 1;           // paired (64-wide) iterations

    const ushort_t* qb = q + (size_t)bh * TT * SS;
    const ushort_t* kb = k + (size_t)bh * TT * SS;
    const ushort_t* vb = v + (size_t)bh * TT * SS;
    const ushort_t* eb = er + (size_t)hh * TT * SS;
    const int l0 = 960 - i0;

    // prologue: Es x in [0,128) -> slots 0..127
    for (int c = tid; c < 1024; c += 512) {
        int row = c >> 3, sub = c & 7;
        int l = l0 + row;
        uint4 val = {0u, 0u, 0u, 0u};
        if ((unsigned)l <= 1023u) val = ((const uint4*)eb)[(size_t)l * 8 + sub];
        *(uint4*)&Es[row][sub * 8] = val;
    }

    const int erow = tid >> 3, esub = tid & 7;   // 64 rows x 8 subs
    const int vjh  = tid >> 6, vd = tid & 63;    // 8 j-octets x 64 d
    uint4 ereg;
    u16x8 vreg;
    {
        const int l = l0 + 128 + erow;           // x in [128,192)
        ereg = (uint4){0u, 0u, 0u, 0u};
        if ((unsigned)l <= 1023u) ereg = ((const uint4*)eb)[(size_t)l * 8 + esub];
#pragma unroll
        for (int jj = 0; jj < 8; jj++)
            vreg[jj] = vb[(size_t)(vjh * 8 + jj) * SS + vd];
    }

    // Q fragments direct from global (once per block; both groups same rows)
    bf16x8 aq[2];
#pragma unroll
    for (int ks = 0; ks < 2; ks++)
        aq[ks] = *(const bf16x8*)&qb[(size_t)(i0 + 16 * wl + m) * SS + ks * 32 + qd * 8];

    f32x4 o[4];
#pragma unroll
    for (int vt = 0; vt < 4; vt++) o[vt] = {0.f, 0.f, 0.f, 0.f};
    float lsum[4] = {0.f, 0.f, 0.f, 0.f};

    const int ow = 48 - 16 * wl;
    const int srcbase = lane & 48;

    int sb = 128;                 // Es write slot base: cycles 128,0,64
    int jm = 32 * grp;            // myj0 mod 192 (cycles, multiples of 32)

    for (int t = 0; t < steps; ++t) {
        // commit staged regs (V: j [64t,64t+64); E: x [64t+128,64t+192))
        *(uint4*)&Es[sb + erow][esub * 8] = ereg;
        *(u16x8*)&Vt4[vjh][vd][0] = vreg;
        __syncthreads();

        // prefetch next paired step
        if (t + 1 < steps) {
            const int jn = 64 * (t + 1);
            const int l = l0 + jn + 128 + erow;
            ereg = (uint4){0u, 0u, 0u, 0u};
            if ((unsigned)l <= 1023u) ereg = ((const uint4*)eb)[(size_t)l * 8 + esub];
#pragma unroll
            for (int jj = 0; jj < 8; jj++)
                vreg[jj] = vb[(size_t)(jn + vjh * 8 + jj) * SS + vd];
        }

        const int myj0 = 64 * t + 32 * grp;

        // QK^T: K gathered direct from global (always in-bounds: j <= i0+63)
        f32x4 s[2];
#pragma unroll
        for (int ct = 0; ct < 2; ct++) {
            s[ct] = {0.f, 0.f, 0.f, 0.f};
#pragma unroll
            for (int ks = 0; ks < 2; ks++) {
                bf16x8 bk = *(const bf16x8*)&kb[(size_t)(myj0 + 16 * ct + m) * SS + ks * 32 + qd * 8];
                s[ct] = __builtin_amdgcn_mfma_f32_16x16x32_bf16(aq[ks], bk, s[ct], 0, 0, 0);
            }
        }
        // Q x Er from the 192-ring
        f32x4 r[3];
#pragma unroll
        for (int rt = 0; rt < 3; rt++) {
            int row0 = jm + ow + 16 * rt;        // multiple of 16, < 192+96
            if (row0 >= 192) row0 -= 192;
            r[rt] = {0.f, 0.f, 0.f, 0.f};
#pragma unroll
            for (int ks = 0; ks < 2; ks++) {
                bf16x8 be = *(const bf16x8*)&Es[row0 + m][ks * 32 + qd * 8];
                r[rt] = __builtin_amdgcn_mfma_f32_16x16x32_bf16(aq[ks], be, r[rt], 0, 0, 0);
            }
        }

        // skew-diagonal extract + softmax numerator (R0 verbatim, j0->myj0)
#pragma unroll
        for (int reg = 0; reg < 4; reg++) {
            const int r_ = qd * 4 + reg;
            const int i_ = i0 + 16 * wl + r_;
            const int base = 15 - r_ + m;
            const int src  = srcbase | (base & 15);
            const float c0 = __shfl(r[0][reg], src);
            const float c1 = __shfl(r[1][reg], src);
            const float c2 = __shfl(r[2][reg], src);
            const float e0 = (base < 16) ? c0 : c1;
            const float e1 = (base < 16) ? c1 : c2;
            const float v0 = s[0][reg] + e0;
            const float v1 = s[1][reg] + e1;
            const float p0 = (myj0 + m      > i_) ? 0.f : __expf(v0);
            const float p1 = (myj0 + m + 16 > i_) ? 0.f : __expf(v1);
            lsum[reg] += p0 + p1;
            Ps[w][r_][m]      = f2b(p0);
            Ps[w][r_][m + 16] = f2b(p1);
        }

        // PV for my 32-j half
        bf16x8 pa = *(const bf16x8*)&Ps[w][m][qd * 8];
#pragma unroll
        for (int vt = 0; vt < 4; vt++) {
            bf16x8 bv = *(const bf16x8*)&Vt4[4 * grp + qd][16 * vt + m][0];
            o[vt] = __builtin_amdgcn_mfma_f32_16x16x32_bf16(pa, bv, o[vt], 0, 0, 0);
        }
        __syncthreads();

        sb = (sb == 128) ? 0 : sb + 64;
        jm += 64;
        if (jm >= 192) jm -= 192;
    }

    // ---- epilogue: combine grp1 partials into grp0 via LDS (over Es) ----
    float* sh = (float*)&Es[0][0];               // 20480 B needed, 27648 free
    const int cidx = ((wl << 6) + lane) * 20;
    if (grp == 1) {
#pragma unroll
        for (int vt = 0; vt < 4; vt++)
#pragma unroll
            for (int reg = 0; reg < 4; reg++) sh[cidx + vt * 4 + reg] = o[vt][reg];
#pragma unroll
        for (int reg = 0; reg < 4; reg++) sh[cidx + 16 + reg] = lsum[reg];
    }
    __syncthreads();
    if (grp == 0) {
#pragma unroll
        for (int vt = 0; vt < 4; vt++)
#pragma unroll
            for (int reg = 0; reg < 4; reg++) o[vt][reg] += sh[cidx + vt * 4 + reg];
#pragma unroll
        for (int reg = 0; reg < 4; reg++) {
            float l = lsum[reg] + sh[cidx + 16 + reg];
#pragma unroll
            for (int off = 1; off < 16; off <<= 1) l += __shfl_xor(l, off);
            const int r_ = qd * 4 + reg;
            const int i_ = i0 + 16 * wl + r_;
            const bool pad = (mask[bb * TT + i_] == 0);
            const float inv = 1.0f / l;
            const size_t rowbase = ((size_t)bb * TT + hh * 64 + (i_ >> 4)) * EE + (i_ & 15) * 64;
#pragma unroll
            for (int vt = 0; vt < 4; vt++) {
                const int d_ = 16 * vt + m;
                float val = pad ? vmean[bh * SS + d_] * (1.0f / 1024.0f)
                                : o[vt][reg] * inv;
                attn[rowbase + d_] = f2b(val);
            }
        }
    }
}

// ---------------------------------------------------------------------------
// Kernel 4: MFMA bf16 GEMM  out = M @ Wo16^T + bo  (unchanged)
// ---------------------------------------------------------------------------
__global__ __launch_bounds__(256) void outproj_kernel(
    const ushort_t* __restrict__ A, const ushort_t* __restrict__ Wo,
    const float* __restrict__ bo, float* __restrict__ out)
{
    __shared__ __align__(16) ushort_t As[128][36];
    __shared__ __align__(16) ushort_t Bs[128][36];

    const int tid  = threadIdx.x;
    const int lane = tid & 63;
    const int w    = tid >> 6;
    const int m    = lane & 15;
    const int qd   = lane >> 4;
    const int wrow = (w & 1) * 64;
    const int wcol = (w >> 1) * 64;
    const int o0   = blockIdx.x * 128;
    const int n0   = blockIdx.y * 128;

    f32x4 acc[4][4];
#pragma unroll
    for (int rt = 0; rt < 4; rt++)
#pragma unroll
        for (int ct = 0; ct < 4; ct++) acc[rt][ct] = {0.f, 0.f, 0.f, 0.f};

    for (int k0 = 0; k0 < 1024; k0 += 32) {
        __syncthreads();
#pragma unroll
        for (int l = 0; l < 2; l++) {
            const int idx = tid + 256 * l;
            const int row = idx >> 2;
            const int sub = idx & 3;
            *(uint4*)&As[row][sub * 8] =
                *(const uint4*)&A[(size_t)(n0 + row) * 1024 + k0 + sub * 8];
            *(uint4*)&Bs[row][sub * 8] =
                *(const uint4*)&Wo[(size_t)(o0 + row) * 1024 + k0 + sub * 8];
        }
        __syncthreads();

        bf16x8 af[4], bf[4];
#pragma unroll
        for (int rt = 0; rt < 4; rt++)
            af[rt] = *(const bf16x8*)&As[wrow + rt * 16 + m][qd * 8];
#pragma unroll
        for (int ct = 0; ct < 4; ct++)
            bf[ct] = *(const bf16x8*)&Bs[wcol + ct * 16 + m][qd * 8];
#pragma unroll
        for (int rt = 0; rt < 4; rt++)
#pragma unroll
            for (int ct = 0; ct < 4; ct++)
                acc[rt][ct] = __builtin_amdgcn_mfma_f32_16x16x32_bf16(
                    af[rt], bf[ct], acc[rt][ct], 0, 0, 0);
    }

#pragma unroll
    for (int rt = 0; rt < 4; rt++) {
#pragma unroll
        for (int ct = 0; ct < 4; ct++) {
            const int oc = o0 + wcol + ct * 16 + m;
            const float bias = bo[oc];
#pragma unroll
            for (int reg = 0; reg < 4; reg++) {
                const int n = n0 + wrow + rt * 16 + qd * 4 + reg;
                out[(size_t)n * EE + oc] = acc[rt][ct][reg] + bias;
            }
        }
    }
}

// ---------------------------------------------------------------------------
// Launcher.  ws (ushort): q16|k16|v16 (4M each) | er16 (1M) | wo16 (1M)
//            | M16 (4M) | vmean f32 (4096)
// ---------------------------------------------------------------------------
extern "C" void kernel_launch(void* const* d_in, const int* in_sizes, int n_in,
                              void* d_out, int out_size, void* d_ws, size_t ws_size,
                              hipStream_t stream)
{
    const float* x    = (const float*)d_in[0];
    const int*   mask = (const int*)d_in[1];
    const float* Wq   = (const float*)d_in[2];
    const float* Wk   = (const float*)d_in[3];
    const float* Wv   = (const float*)d_in[4];
    const float* Er   = (const float*)d_in[5];
    const float* Wo   = (const float*)d_in[6];
    const float* bo   = (const float*)d_in[7];
    float* out = (float*)d_out;

    const size_t QKV = (size_t)BB * HH * TT * SS;
    const int    nEr = HH * TT * SS;
    const int    nWo = EE * EE;
    ushort_t* q16   = (ushort_t*)d_ws;
    ushort_t* k16   = q16 + QKV;
    ushort_t* v16   = k16 + QKV;
    ushort_t* er16  = v16 + QKV;
    ushort_t* wo16  = er16 + nEr;
    ushort_t* M16   = wo16 + nWo;
    float*    vmean = (float*)(M16 + QKV);

    hipMemsetAsync(vmean, 0, BB * HH * SS * sizeof(float), stream);
    cvt2_kernel<<<dim3((nEr + nWo) / 1024), 256, 0, stream>>>(Er, er16, nEr, Wo, wo16, nWo);
    qkv_kernel<<<dim3(BB * TT / 128, HH), 256, 0, stream>>>(x, Wq, Wk, Wv, q16, k16, v16, vmean);
    attn_kernel<<<dim3(BB * HH, TT / 64), 512, 0, stream>>>(q16, k16, v16, er16, mask, vmean, M16);
    outproj_kernel<<<dim3(EE / 128, BB * TT / 128), 256, 0, stream>>>(M16, wo16, bo, out);
}